// Round 6
// baseline (140.439 us; speedup 1.0000x reference)
//
#include <hip/hip_runtime.h>
#include <hip/hip_bf16.h>
#include <stdint.h>

// Problem shape (fixed by reference)
#define B_ 32
#define T_ 1024
#define J_ 256
#define D_ 512

typedef __attribute__((ext_vector_type(8))) short short8;   // 8 bf16 (4 VGPRs)
typedef __attribute__((ext_vector_type(4))) float floatx4;  // MFMA C/D frag

// ---------------------------------------------------------------------------
// Kernel 1: prep_u — B2[j,k] = bf16(u[j,k]*w_m[k] + w_h[k]),
//                    tu[j]   = sum_k u[j,k]*w_u[k]   (fp32)
// Identity: out[t,j] = sum_k h[t,k]*B2[j,k] + tu[j]
// ---------------------------------------------------------------------------
__global__ __launch_bounds__(256) void prep_u_kernel(
    const float* __restrict__ u, const float* __restrict__ w,
    __hip_bfloat16* __restrict__ B2, float* __restrict__ tu)
{
    int row  = blockIdx.x * 4 + (threadIdx.x >> 6);   // one wave per u-row
    int lane = threadIdx.x & 63;
    const float* src = u + (size_t)row * D_;
    int base = lane * 8;

    float4 v0  = *(const float4*)(src + base);
    float4 v1  = *(const float4*)(src + base + 4);
    float4 wh0 = *(const float4*)(w + base);            // w_h = w[0:512]
    float4 wh1 = *(const float4*)(w + base + 4);
    float4 wu0 = *(const float4*)(w + D_ + base);       // w_u = w[512:1024]
    float4 wu1 = *(const float4*)(w + D_ + base + 4);
    float4 wm0 = *(const float4*)(w + 2*D_ + base);     // w_m = w[1024:1536]
    float4 wm1 = *(const float4*)(w + 2*D_ + base + 4);

    float s = v0.x*wu0.x + v0.y*wu0.y + v0.z*wu0.z + v0.w*wu0.w
            + v1.x*wu1.x + v1.y*wu1.y + v1.z*wu1.z + v1.w*wu1.w;

    float vals[8] = {
        v0.x*wm0.x + wh0.x, v0.y*wm0.y + wh0.y,
        v0.z*wm0.z + wh0.z, v0.w*wm0.w + wh0.w,
        v1.x*wm1.x + wh1.x, v1.y*wm1.y + wh1.y,
        v1.z*wm1.z + wh1.z, v1.w*wm1.w + wh1.w };

    union { __hip_bfloat16 b[8]; uint4 q; } pk;
#pragma unroll
    for (int i = 0; i < 8; i++) pk.b[i] = __float2bfloat16(vals[i]);
    *(uint4*)(B2 + (size_t)row * D_ + base) = pk.q;     // 16B coalesced store

#pragma unroll
    for (int off = 32; off > 0; off >>= 1) s += __shfl_down(s, off, 64);
    if (lane == 0) tu[row] = s;
}

// ---------------------------------------------------------------------------
// Kernel 2: fused GEMM  out[b] = bf16(h[b]) @ B2[b]^T + tu
//
// Round-6: pure producer-consumer K-loop — ZERO per-lane global loads.
//  - 64x128 tile, 256 threads (4 waves, 2x2 grid), 1024 blocks = 4/CU.
//  - A (= h, fp32 RAW BYTES) and B2 (bf16) both staged by async
//    global_load_lds DMA, double-buffered (LDS 32 KB/block).
//  - 16 K-phases of 32: stage p+1 (async, 4 DMAs/thread), compute p from
//    LDS only (ds_read_b128 + cvt + MFMA), __syncthreads. The vmcnt(0)
//    drain at the barrier waits only on DMAs aged a full phase (~2500 cyc
//    of HBM-bound wall vs ~900 cyc load latency) -> free.
//  - fp32->bf16 cvt happens after the LDS read (VALU, overlapped).
// LDS maps (chunk = 16 B):
//  - sA: row j (64) x 8 chunks; source chunk c stored at slot c^(j&7)
//    (without swizzle, frag reads hit only even bank-groups = 2x conflict).
//  - sB: row j (128) x 4 chunks, row-major — natively uniform-8 for both
//    staging and frag reads (group = (4j+kq)&7 covers all 8).
// ---------------------------------------------------------------------------
__device__ inline void gload_lds16(const void* g, void* l) {
    __builtin_amdgcn_global_load_lds(
        (__attribute__((address_space(1))) void*)(g),
        (__attribute__((address_space(3))) void*)(l),
        16, 0, 0);
}

__global__ __launch_bounds__(256, 4) void gemm_kernel(
    const float* __restrict__ h,            // [B, T, D] fp32
    const __hip_bfloat16* __restrict__ B2,  // [B, J, D] bf16 (= u*w_m + w_h)
    const float* __restrict__ tu,           // [B*J] fp32
    float* __restrict__ out)                // [B, T, J] fp32
{
    __shared__ __align__(16) float          sA[2][64 * 32];   // 2 x 8 KB
    __shared__ __align__(16) __hip_bfloat16 sB[2][128 * 32];  // 2 x 8 KB

    const int b   = blockIdx.y;
    const int tM  = blockIdx.x >> 1;        // T/64 = 16
    const int tN  = blockIdx.x & 1;         // J/128 = 2
    const int tid = threadIdx.x;
    const int w = tid >> 6, lane = tid & 63;
    const int wr = w >> 1, wc = w & 1;      // 2x2 wave grid: 32x64 per wave
    const int fr = lane & 15;               // m/n within 16-tile
    const int kq = lane >> 4;               // k-quarter 0..3

    const float*          Ab = h  + ((size_t)b * T_ + tM * 64) * D_;
    const __hip_bfloat16* Bb = B2 + ((size_t)b * J_ + tN * 128) * D_;

    // A staging: 512 chunks/phase, 2 per thread. q = i*256+tid,
    // j = q>>3, source chunk c = (q&7)^(j&7), LDS slot = q (lane-linear).
    int ajr[2], acs[2];
#pragma unroll
    for (int i = 0; i < 2; i++) {
        int q = i * 256 + tid;
        ajr[i] = q >> 3;
        acs[i] = (q & 7) ^ (ajr[i] & 7);
    }
    // B staging: 512 chunks/phase, 2 per thread, row-major (no swizzle).
    int bjr[2];
#pragma unroll
    for (int i = 0; i < 2; i++) bjr[i] = (i * 256 + tid) >> 2;
    const int bcs = tid & 3;

    floatx4 acc[2][4];
#pragma unroll
    for (int i = 0; i < 2; i++)
#pragma unroll
        for (int j = 0; j < 4; j++) acc[i][j] = (floatx4)0.0f;

    // ---- stage phase 0
#pragma unroll
    for (int i = 0; i < 2; i++)
        gload_lds16(Ab + (size_t)ajr[i] * D_ + acs[i] * 4,
                    &sA[0][(i * 256 + tid) * 4]);
#pragma unroll
    for (int i = 0; i < 2; i++)
        gload_lds16(Bb + (size_t)bjr[i] * D_ + bcs * 8,
                    &sB[0][(i * 256 + tid) * 8]);
    __syncthreads();

    for (int p = 0; p < 16; p++) {
        // ---- async prefetch of phase p+1 into the other buffer
        if (p < 15) {
            int k0 = (p + 1) * 32;
            int nb = (p + 1) & 1;
#pragma unroll
            for (int i = 0; i < 2; i++)
                gload_lds16(Ab + (size_t)ajr[i] * D_ + k0 + acs[i] * 4,
                            &sA[nb][(i * 256 + tid) * 4]);
#pragma unroll
            for (int i = 0; i < 2; i++)
                gload_lds16(Bb + (size_t)bjr[i] * D_ + k0 + bcs * 8,
                            &sB[nb][(i * 256 + tid) * 8]);
        }

        // ---- compute phase p: LDS-only reads
        const float*          sAp = sA[p & 1];
        const __hip_bfloat16* sBp = sB[p & 1];

        short8 bfr[4];
#pragma unroll
        for (int ni = 0; ni < 4; ni++) {
            int jb = wc * 64 + ni * 16 + fr;
            bfr[ni] = *(const short8*)(sBp + (jb * 4 + kq) * 8);
        }
        short8 af[2];
#pragma unroll
        for (int mi = 0; mi < 2; mi++) {
            int ja = wr * 32 + mi * 16 + fr;
            int s0 = (2 * kq)     ^ (ja & 7);
            int s1 = (2 * kq + 1) ^ (ja & 7);
            float4 x0 = *(const float4*)(sAp + (ja * 8 + s0) * 4);
            float4 x1 = *(const float4*)(sAp + (ja * 8 + s1) * 4);
            union { __hip_bfloat16 e[8]; short8 v; } pk;
            pk.e[0]=__float2bfloat16(x0.x); pk.e[1]=__float2bfloat16(x0.y);
            pk.e[2]=__float2bfloat16(x0.z); pk.e[3]=__float2bfloat16(x0.w);
            pk.e[4]=__float2bfloat16(x1.x); pk.e[5]=__float2bfloat16(x1.y);
            pk.e[6]=__float2bfloat16(x1.z); pk.e[7]=__float2bfloat16(x1.w);
            af[mi] = pk.v;
        }
#pragma unroll
        for (int mi = 0; mi < 2; mi++)
#pragma unroll
            for (int ni = 0; ni < 4; ni++)
                acc[mi][ni] = __builtin_amdgcn_mfma_f32_16x16x32_bf16(
                    af[mi], bfr[ni], acc[mi][ni], 0, 0, 0);

        __syncthreads();   // drain = DMAs aged one phase (~free) + LDS handoff
    }

    // epilogue: C/D layout col = lane&15, row = (lane>>4)*4 + reg  [m89/m91]
    const size_t outB = (size_t)b * T_ * J_;
    const float* tub = tu + b * J_;
#pragma unroll
    for (int mi = 0; mi < 2; mi++) {
        int r0 = tM * 64 + wr * 32 + mi * 16 + kq * 4;
#pragma unroll
        for (int ni = 0; ni < 4; ni++) {
            int col = tN * 128 + wc * 64 + ni * 16 + fr;
            float tuv = tub[col];
#pragma unroll
            for (int r = 0; r < 4; r++) {
                out[outB + (size_t)(r0 + r) * J_ + col] = acc[mi][ni][r] + tuv;
            }
        }
    }
}

// ---------------------------------------------------------------------------
extern "C" void kernel_launch(void* const* d_in, const int* in_sizes, int n_in,
                              void* d_out, int out_size, void* d_ws, size_t ws_size,
                              hipStream_t stream)
{
    const float* h = (const float*)d_in[0];
    const float* u = (const float*)d_in[1];
    const float* w = (const float*)d_in[2];
    float* out = (float*)d_out;

    uint8_t* ws = (uint8_t*)d_ws;
    __hip_bfloat16* B2 = (__hip_bfloat16*)ws;                 // 8 MiB
    float* tu = (float*)(ws + (size_t)B_ * J_ * D_ * 2);      // 32 KiB

    // one wave per u-row; 4 rows per 256-thread block; 8192 rows total
    prep_u_kernel<<<dim3(B_ * J_ / 4), 256, 0, stream>>>(u, w, B2, tu);

    // 64x128 tiles: (T/64)*(J/128) = 32 tiles/batch, 32 batches = 1024 blocks
    gemm_kernel<<<dim3((T_ / 64) * (J_ / 128), B_), 256, 0, stream>>>(h, B2, tu, out);
}